// Round 7
// baseline (1114.703 us; speedup 1.0000x reference)
//
#include <hip/hip_runtime.h>
#include <math.h>
#include <stdint.h>

#define N_HEADS 4
#define N_NODES 10000
#define NPAD 10048           /* rounded up to multiple of TN */
#define EMB 128
#define N_BATCH 4096
#define NQ (2 * N_BATCH)     /* 8192 queries: [src(4096), dst(4096)] */
#define K 8
#define TQ 64
#define TN 64
#define NTILES (NPAD / TN)   /* 157 */
#define PH 4                 /* warm-up tiles using s_x dump + private insert */
#define CAP 33               /* per-query candidate list capacity (odd: bank-safe) */

typedef __attribute__((ext_vector_type(8))) __bf16 bf16x8;
typedef __attribute__((ext_vector_type(16))) float floatx16;

// ---------------------------------------------------------------------------
// helpers
// ---------------------------------------------------------------------------
__device__ __forceinline__ unsigned short f2bf(float x) {
  unsigned u = __float_as_uint(x);
  u += 0x7fff + ((u >> 16) & 1);           // round-to-nearest-even
  return (unsigned short)(u >> 16);
}
__device__ __forceinline__ float bf2f(unsigned short h) {
  return __uint_as_float(((unsigned)h) << 16);
}

// sorted ascending top-8 insertion
__device__ __forceinline__ void insert8(float* bs, int* bi, float s, int node) {
  if (s < bs[K - 1]) {
    #pragma unroll
    for (int k2 = K - 1; k2 >= 0; --k2) {
      if (!(s < bs[k2])) break;
      if (k2 < K - 1) { bs[k2 + 1] = bs[k2]; bi[k2 + 1] = bi[k2]; }
      bs[k2] = s; bi[k2] = node;
    }
  }
}

// ---------------------------------------------------------------------------
// Kernel P: split E into bf16 hi/lo (padded to NPAD rows) + squared norms.
// ---------------------------------------------------------------------------
__global__ __launch_bounds__(256) void prep_kernel(
    const float* __restrict__ E, unsigned short* __restrict__ Ehi,
    unsigned short* __restrict__ Elo, float* __restrict__ y2g) {
  int h = blockIdx.y;
  int n = blockIdx.x * 4 + (threadIdx.x >> 6);
  int lane = threadIdx.x & 63;
  float2 x = make_float2(0.f, 0.f);
  if (n < N_NODES)
    x = *(const float2*)(E + (size_t)(h * N_NODES + n) * EMB + 2 * lane);
  unsigned short h0 = f2bf(x.x), h1 = f2bf(x.y);
  unsigned short l0 = f2bf(x.x - bf2f(h0)), l1 = f2bf(x.y - bf2f(h1));
  size_t orow = (size_t)(h * NPAD + n) * EMB;
  ((ushort2*)(Ehi + orow))[lane] = make_ushort2(h0, h1);
  ((ushort2*)(Elo + orow))[lane] = make_ushort2(l0, l1);
  float s = x.x * x.x + x.y * x.y;
  #pragma unroll
  for (int o = 32; o > 0; o >>= 1) s += __shfl_xor(s, o);
  if (lane == 0) y2g[h * NPAD + n] = (n < N_NODES) ? s : 1e30f;
}

// ---------------------------------------------------------------------------
// Kernel A: barrier-free MFMA knn.
// Grid (NQ/TQ=128, N_HEADS), 256 threads. Wave (w0,w1) owns the 32x32 tile
// at query rows 32*w0, node cols 32*w1. A-frags (query hi+lo) in registers
// for the whole kernel. B-frags load DIRECTLY global->VGPR each tile (a
// wave's 32-node strip is 8 KiB contiguous; L1/L2-resident) — no LDS tile,
// no DMA, no per-tile __syncthreads.
//
// Selection: warm-up (PH tiles) dumps scores to s_x and builds per-query
// private top-8 (4 scan threads/query, self excluded). Merge at u=4 builds
// per-query exact top-8 + threshold. Steady state: in-register compare of
// each score vs thr16[] (cached per-lane, refreshed at merges); survivors
// (rare, ~10/query/epoch) append to per-query LDS lists via atomicAdd.
// Stale (looser) thresholds between merges are conservative => exact.
// Merges at u=8,16,32,64 and end fold lists into top-8. Self node passes
// the filter once and is excluded at merge. score = y2[n]-2*dot.
// ---------------------------------------------------------------------------
__global__ __launch_bounds__(256, 2) void knn_kernel(
    const unsigned short* __restrict__ Ehi, const unsigned short* __restrict__ Elo,
    const float* __restrict__ y2g, const int* __restrict__ be,
    int* __restrict__ samples) {
  __shared__ __align__(16) float s_x[TQ * TN];   // 16 KiB: q-staging / warm-up scores / scratch
  __shared__ float s_t8S[TQ * 9];                // running top-8 (stride 9: bank-safe)
  __shared__ int   s_t8I[TQ * 9];
  __shared__ float s_lsS[TQ * CAP];              // candidate lists
  __shared__ int   s_lsI[TQ * CAP];
  __shared__ float s_thr[TQ];
  __shared__ int   s_cnt[TQ];

  const int h = blockIdx.y, tile = blockIdx.x, tid = threadIdx.x;
  const int wave = tid >> 6, lane = tid & 63;
  const int w0 = wave >> 1, w1 = wave & 1;
  const int lm = lane & 31, lh = lane >> 5;
  const unsigned short* EhiH = Ehi + (size_t)h * NPAD * EMB;
  const unsigned short* EloH = Elo + (size_t)h * NPAD * EMB;
  const float* y2H = y2g + h * NPAD;

  // ---- prologue: stage gathered query rows through s_x (swizzled), load A ----
  bf16x8 ahi[8], alo[8];
  unsigned short* s_xq = (unsigned short*)s_x;
  {
    int r = tid >> 2, cbase = (tid & 3) * 4;    // 4 chunks of 8 ushort each
    int rx15 = r & 15;
    int q = be[tile * TQ + r];
    const int arow = 32 * w0 + lm;
    const int arx = arow & 15;
    const unsigned short* src = EhiH + (size_t)q * EMB;
    #pragma unroll
    for (int c = 0; c < 4; ++c) {
      int lc = cbase + c;
      *(bf16x8*)&s_xq[r * EMB + (lc ^ rx15) * 8] = *(const bf16x8*)&src[lc * 8];
    }
    __syncthreads();
    #pragma unroll
    for (int ks = 0; ks < 8; ++ks)
      ahi[ks] = *(const bf16x8*)&s_xq[arow * EMB + (((ks * 2 + lh) ^ arx)) * 8];
    __syncthreads();
    src = EloH + (size_t)q * EMB;
    #pragma unroll
    for (int c = 0; c < 4; ++c) {
      int lc = cbase + c;
      *(bf16x8*)&s_xq[r * EMB + (lc ^ rx15) * 8] = *(const bf16x8*)&src[lc * 8];
    }
    __syncthreads();
    #pragma unroll
    for (int ks = 0; ks < 8; ++ks)
      alo[ks] = *(const bf16x8*)&s_xq[arow * EMB + (((ks * 2 + lh) ^ arx)) * 8];
    __syncthreads();
  }

  // warm-up scan roles: 4 threads per query, each owns a 16-col stripe
  const int qsel = tid >> 2;
  const int csel = tid & 3;
  const int myq = be[tile * TQ + qsel];
  float bs[K]; int bi[K];
  #pragma unroll
  for (int k2 = 0; k2 < K; ++k2) { bs[k2] = 1e30f; bi[k2] = 0x7fffffff; }
  if (tid < TQ) s_cnt[tid] = 0;

  // this lane's B-strip base (nodes 32*w1+lm of each tile) and row offsets
  const int bnode = 32 * w1 + lm;                 // node within tile
  const unsigned short* bhp = EhiH + (size_t)bnode * EMB + lh * 8;
  const unsigned short* blp = EloH + (size_t)bnode * EMB + lh * 8;

  // ---- warm-up: PH tiles via score dump + private insert ----
  #pragma unroll 1
  for (int t = 0; t < PH; ++t) {
    const size_t goff = (size_t)t * TN * EMB;
    float ny = y2H[t * TN + bnode];
    floatx16 acc = {0.f, 0.f, 0.f, 0.f, 0.f, 0.f, 0.f, 0.f,
                    0.f, 0.f, 0.f, 0.f, 0.f, 0.f, 0.f, 0.f};
    #pragma unroll
    for (int ks = 0; ks < 8; ++ks) {
      bf16x8 vbh = *(const bf16x8*)(bhp + goff + ks * 16);
      bf16x8 vbl = *(const bf16x8*)(blp + goff + ks * 16);
      acc = __builtin_amdgcn_mfma_f32_32x32x16_bf16(alo[ks], vbh, acc, 0, 0, 0);
      acc = __builtin_amdgcn_mfma_f32_32x32x16_bf16(ahi[ks], vbl, acc, 0, 0, 0);
      acc = __builtin_amdgcn_mfma_f32_32x32x16_bf16(ahi[ks], vbh, acc, 0, 0, 0);
    }
    #pragma unroll
    for (int r = 0; r < 16; ++r) {
      int row = (r & 3) + 8 * (r >> 2) + 4 * lh;
      s_x[(32 * w0 + row) * TN + bnode] = fmaf(-2.f, acc[r], ny);
    }
    __syncthreads();
    int nbp = t * TN;
    #pragma unroll
    for (int s = 0; s < 16; ++s) {
      int j = csel * 16 + ((s + qsel) & 15);
      float sc = s_x[qsel * TN + j];
      int node = nbp + j;
      if (node != myq) insert8(bs, bi, sc, node);
    }
    __syncthreads();
  }

  // ---- first merge: privates -> exact top-8 + thresholds ----
  {
    float* scrS = (float*)s_x;
    int*   scrI = (int*)s_x + TQ * 32;
    #pragma unroll
    for (int k2 = 0; k2 < K; ++k2) {
      scrS[tid * 8 + k2] = bs[k2]; scrI[tid * 8 + k2] = bi[k2];
    }
    __syncthreads();
    if (tid < TQ) {
      int q = tid;
      float ts[K]; int ti[K];
      #pragma unroll
      for (int k2 = 0; k2 < K; ++k2) { ts[k2] = 1e30f; ti[k2] = 0x7fffffff; }
      for (int kk = 0; kk < 32; ++kk) {
        int e = (kk + q) & 31;                     // bank-rotated scan
        insert8(ts, ti, scrS[q * 32 + e], scrI[q * 32 + e]);
      }
      s_thr[q] = ts[K - 1];
      #pragma unroll
      for (int k2 = 0; k2 < K; ++k2) { s_t8S[q * 9 + k2] = ts[k2]; s_t8I[q * 9 + k2] = ti[k2]; }
    }
    __syncthreads();
  }

  float thr16[16];
  #pragma unroll
  for (int r = 0; r < 16; ++r)
    thr16[r] = s_thr[32 * w0 + (r & 3) + 8 * (r >> 2) + 4 * lh];

  // ---- steady state: barrier-free tiles with in-register filtering ----
  #pragma unroll 1
  for (int t = PH; t < NTILES; ++t) {
    const int u = t;
    if (u == 8 || u == 16 || u == 32 || u == 64) {   // merge point
      __syncthreads();                                // all appends for u<t visible
      if (tid < TQ) {
        int q = tid;
        int myqm = be[tile * TQ + q];
        float ts[K]; int ti[K];
        #pragma unroll
        for (int k2 = 0; k2 < K; ++k2) { ts[k2] = s_t8S[q * 9 + k2]; ti[k2] = s_t8I[q * 9 + k2]; }
        int cnt = s_cnt[q]; if (cnt > CAP) cnt = CAP;
        for (int p = 0; p < cnt; ++p) {
          int iv = s_lsI[q * CAP + p];
          if (iv != myqm) insert8(ts, ti, s_lsS[q * CAP + p], iv);
        }
        s_cnt[q] = 0;
        s_thr[q] = ts[K - 1];
        #pragma unroll
        for (int k2 = 0; k2 < K; ++k2) { s_t8S[q * 9 + k2] = ts[k2]; s_t8I[q * 9 + k2] = ti[k2]; }
      }
      __syncthreads();
      #pragma unroll
      for (int r = 0; r < 16; ++r)
        thr16[r] = s_thr[32 * w0 + (r & 3) + 8 * (r >> 2) + 4 * lh];
    }

    const size_t goff = (size_t)t * TN * EMB;
    float ny = y2H[t * TN + bnode];
    floatx16 acc = {0.f, 0.f, 0.f, 0.f, 0.f, 0.f, 0.f, 0.f,
                    0.f, 0.f, 0.f, 0.f, 0.f, 0.f, 0.f, 0.f};
    #pragma unroll
    for (int ks = 0; ks < 8; ++ks) {
      bf16x8 vbh = *(const bf16x8*)(bhp + goff + ks * 16);
      bf16x8 vbl = *(const bf16x8*)(blp + goff + ks * 16);
      acc = __builtin_amdgcn_mfma_f32_32x32x16_bf16(alo[ks], vbh, acc, 0, 0, 0);
      acc = __builtin_amdgcn_mfma_f32_32x32x16_bf16(ahi[ks], vbl, acc, 0, 0, 0);
      acc = __builtin_amdgcn_mfma_f32_32x32x16_bf16(ahi[ks], vbh, acc, 0, 0, 0);
    }
    const int node = t * TN + bnode;
    #pragma unroll
    for (int r = 0; r < 16; ++r) {
      float sc = fmaf(-2.f, acc[r], ny);
      if (sc < thr16[r]) {                          // rare (self or new top-8)
        int q = 32 * w0 + (r & 3) + 8 * (r >> 2) + 4 * lh;
        int p = atomicAdd(&s_cnt[q], 1);
        if (p < CAP) { s_lsS[q * CAP + p] = sc; s_lsI[q * CAP + p] = node; }
      }
    }
  }

  // ---- final merge + writeout ----
  __syncthreads();
  if (tid < TQ) {
    int q = tid;
    int myqm = be[tile * TQ + q];
    float ts[K]; int ti[K];
    #pragma unroll
    for (int k2 = 0; k2 < K; ++k2) { ts[k2] = s_t8S[q * 9 + k2]; ti[k2] = s_t8I[q * 9 + k2]; }
    int cnt = s_cnt[q]; if (cnt > CAP) cnt = CAP;
    for (int p = 0; p < cnt; ++p) {
      int iv = s_lsI[q * CAP + p];
      if (iv != myqm) insert8(ts, ti, s_lsS[q * CAP + p], iv);
    }
    size_t base = ((size_t)h * NQ + tile * TQ + q) * K;
    #pragma unroll
    for (int k2 = 0; k2 < K; ++k2) samples[base + k2] = ti[k2];
  }
}

// ---------------------------------------------------------------------------
// Kernel B: epilogue (unchanged — verified absmax 0.0).
// ---------------------------------------------------------------------------
__global__ __launch_bounds__(256) void predict_kernel(
    const float* __restrict__ E, const float* __restrict__ F,
    const float* __restrict__ unc, const float* __restrict__ adj,
    const int* __restrict__ be, const int* __restrict__ samples,
    float* __restrict__ out) {
  int b = blockIdx.x;
  int h = threadIdx.x >> 6;
  int lane = threadIdx.x & 63;
  __shared__ float smv[N_HEADS];

  int srcb = be[b];
  int dstb = be[N_BATCH + b];
  const float* Eh = E + (size_t)h * N_NODES * EMB;
  const float* Fh = F + (size_t)h * N_NODES * EMB;
  float2 es = *(const float2*)(Eh + (size_t)srcb * EMB + 2 * lane);
  float2 ed = *(const float2*)(Eh + (size_t)dstb * EMB + 2 * lane);
  float2 fs = *(const float2*)(Fh + (size_t)srcb * EMB + 2 * lane);
  float2 fd = *(const float2*)(Fh + (size_t)dstb * EMB + 2 * lane);
  float u = unc[0];

  float logit[16], dist[16];
  #pragma unroll
  for (int j = 0; j < 16; ++j) {
    bool isrc = (j < 8);
    int qrow = isrc ? b : (N_BATCH + b);
    int s = samples[((size_t)h * NQ + qrow) * K + (j & 7)];
    float2 ev = *(const float2*)(Eh + (size_t)s * EMB + 2 * lane);
    float2 bb = isrc ? es : ed;
    float2 g = isrc ? fd : fs;
    float dx = bb.x - ev.x, dy = bb.y - ev.y;
    float dot = dx * g.x + dy * g.y;
    float nrm = dx * dx + dy * dy;
    #pragma unroll
    for (int o = 32; o > 0; o >>= 1) {
      dot += __shfl_xor(dot, o);
      nrm += __shfl_xor(nrm, o);
    }
    float a = isrc ? adj[(size_t)s * N_NODES + dstb]
                   : adj[(size_t)srcb * N_NODES + s];
    logit[j] = dot + u * (2.0f * a - 1.0f);
    dist[j] = sqrtf(nrm);
  }

  float m = 0.0f;  // sentinel: 1 - 1.0 = 0
  #pragma unroll
  for (int j = 0; j < 16; ++j) m = fmaxf(m, 1.0f - dist[j]);
  float Z = 8.0f * expf(-m);
  float num = 0.0f;
  #pragma unroll
  for (int j = 0; j < 16; ++j) {
    float e = expf(1.0f - dist[j] - m);
    Z += e;
    num += logit[j] * e;
  }
  if (lane == 0) smv[h] = num / Z;
  __syncthreads();
  if (threadIdx.x == 0) {
    float t = 0.25f * (smv[0] + smv[1] + smv[2] + smv[3]);
    out[b] = 1.0f / (1.0f + expf(-t));
  }
}

// ---------------------------------------------------------------------------
extern "C" void kernel_launch(void* const* d_in, const int* in_sizes, int n_in,
                              void* d_out, int out_size, void* d_ws,
                              size_t ws_size, hipStream_t stream) {
  const float* E = (const float*)d_in[0];
  const float* F = (const float*)d_in[1];
  const float* U = (const float*)d_in[2];
  const float* A = (const float*)d_in[3];
  const int* be = (const int*)d_in[4];
  float* out = (float*)d_out;

  // ws layout (256B-aligned): Ehi 10,289,152 | Elo 10,289,152 |
  //   y2g 160,768 | samples 1,048,576   (~21.8 MB)
  char* w = (char*)d_ws;
  unsigned short* Ehi = (unsigned short*)(w);
  unsigned short* Elo = (unsigned short*)(w + 10289152);
  float* y2g = (float*)(w + 20578304);
  int* samples = (int*)(w + 20739072);

  prep_kernel<<<dim3(NPAD / 4, N_HEADS), 256, 0, stream>>>(E, Ehi, Elo, y2g);
  knn_kernel<<<dim3(NQ / TQ, N_HEADS), 256, 0, stream>>>(Ehi, Elo, y2g, be, samples);
  predict_kernel<<<dim3(N_BATCH), 256, 0, stream>>>(E, F, U, A, be, samples, out);
}

// Round 8
// 941.116 us; speedup vs baseline: 1.1844x; 1.1844x over previous
//
#include <hip/hip_runtime.h>
#include <math.h>
#include <stdint.h>

#define N_HEADS 4
#define N_NODES 10000
#define NPAD 10048           /* multiple of 64 */
#define NPG (NPAD / 32)      /* 314 node-groups of 32 */
#define EMB 128
#define N_BATCH 4096
#define NQ (2 * N_BATCH)     /* 8192 queries: [src(4096), dst(4096)] */
#define K 8
#define TQ 64
#define TN 64
#define NTILES (NPAD / TN)   /* 157 */
#define PH 4                 /* warm-up tiles using s_x dump + private insert */
#define CAP 33               /* per-query candidate list capacity (odd: bank-safe) */

typedef __attribute__((ext_vector_type(8))) __bf16 bf16x8;
typedef __attribute__((ext_vector_type(16))) float floatx16;

// ---------------------------------------------------------------------------
// helpers
// ---------------------------------------------------------------------------
__device__ __forceinline__ unsigned short f2bf(float x) {
  unsigned u = __float_as_uint(x);
  u += 0x7fff + ((u >> 16) & 1);           // round-to-nearest-even
  return (unsigned short)(u >> 16);
}
__device__ __forceinline__ float bf2f(unsigned short h) {
  return __uint_as_float(((unsigned)h) << 16);
}

// sorted ascending top-8 insertion
__device__ __forceinline__ void insert8(float* bs, int* bi, float s, int node) {
  if (s < bs[K - 1]) {
    #pragma unroll
    for (int k2 = K - 1; k2 >= 0; --k2) {
      if (!(s < bs[k2])) break;
      if (k2 < K - 1) { bs[k2 + 1] = bs[k2]; bi[k2 + 1] = bi[k2]; }
      bs[k2] = s; bi[k2] = node;
    }
  }
}

// permuted chunk offset (in ushorts) for row (32g+lm), chunk c = ks*2+lh
// layout: [g][ks][lh][lm] x 8 ushorts  => g*4096 + ks*512 + lh*256 + lm*8
__device__ __forceinline__ size_t pchunk(int g, int c, int lm) {
  return (size_t)g * 4096 + (size_t)(c >> 1) * 512 + (size_t)(c & 1) * 256 + lm * 8;
}

// ---------------------------------------------------------------------------
// Kernel P: split E into bf16 hi/lo in MFMA-B-fragment-permuted layout.
// Grid (NPG, N_HEADS), 256 thr. Thread (lm=tid&31, c8=tid>>5) handles row
// 32g+lm, k-range [c8*16, c8*16+16). Pad rows -> zeros.
// ---------------------------------------------------------------------------
__global__ __launch_bounds__(256) void prep_kernel(
    const float* __restrict__ E, unsigned short* __restrict__ EhiP,
    unsigned short* __restrict__ EloP) {
  const int h = blockIdx.y, g = blockIdx.x;
  const int lm = threadIdx.x & 31, c8 = threadIdx.x >> 5;
  const int n = g * 32 + lm;
  float x[16];
  #pragma unroll
  for (int j = 0; j < 16; ++j) x[j] = 0.f;
  if (n < N_NODES) {
    const float* src = E + (size_t)(h * N_NODES + n) * EMB + c8 * 16;
    #pragma unroll
    for (int j = 0; j < 4; ++j) {
      float4 v = *(const float4*)(src + j * 4);
      x[j * 4 + 0] = v.x; x[j * 4 + 1] = v.y; x[j * 4 + 2] = v.z; x[j * 4 + 3] = v.w;
    }
  }
  unsigned short hi[16], lo[16];
  #pragma unroll
  for (int j = 0; j < 16; ++j) {
    hi[j] = f2bf(x[j]);
    lo[j] = f2bf(x[j] - bf2f(hi[j]));
  }
  size_t base = (size_t)h * NPG * 4096;
  #pragma unroll
  for (int lh = 0; lh < 2; ++lh) {
    size_t off = base + pchunk(g, c8 * 2 + lh, lm);
    #pragma unroll
    for (int j = 0; j < 8; ++j) {
      EhiP[off + j] = hi[lh * 8 + j];
      EloP[off + j] = lo[lh * 8 + j];
    }
  }
}

// ---------------------------------------------------------------------------
// Kernel Y: y2[h][n] = ||E[h][n]||^2 (1e30 on pad rows). One wave per (h,n).
// ---------------------------------------------------------------------------
__global__ __launch_bounds__(256) void y2_kernel(const float* __restrict__ E,
                                                 float* __restrict__ y2g) {
  int h = blockIdx.y;
  int n = blockIdx.x * 4 + (threadIdx.x >> 6);
  int lane = threadIdx.x & 63;
  float s = 0.f;
  if (n < N_NODES) {
    float2 p = *(const float2*)(E + (size_t)(h * N_NODES + n) * EMB + 2 * lane);
    s = p.x * p.x + p.y * p.y;
  }
  #pragma unroll
  for (int o = 32; o > 0; o >>= 1) s += __shfl_xor(s, o);
  if (lane == 0 && n < NPAD) y2g[h * NPAD + n] = (n < N_NODES) ? s : 1e30f;
}

// ---------------------------------------------------------------------------
// Kernel A: barrier-free MFMA knn with COALESCED B loads.
// Grid (NQ/TQ=128, N_HEADS), 256 threads. Wave (w0,w1) owns the 32x32 tile
// at query rows 32*w0, node group 2t+w1. A-frags (query hi+lo) in registers.
// B-frags load global->VGPR from the permuted layout: for (tile,ks) a wave
// reads base+(2t+w1)*8KiB+ks*1KiB+lane*16B — lane-linear 1 KiB, fully
// coalesced. No LDS tile, no per-tile barriers.
// Selection: identical to R7 (verified): warm-up private insert -> merged
// per-query top-8 + thresholds; steady state in-register filter + rare LDS
// list append; merges at u=8/16/32/64/end. score = y2[n]-2*dot.
// ---------------------------------------------------------------------------
__global__ __launch_bounds__(256, 3) void knn_kernel(
    const unsigned short* __restrict__ EhiP, const unsigned short* __restrict__ EloP,
    const float* __restrict__ y2g, const int* __restrict__ be,
    int* __restrict__ samples) {
  __shared__ __align__(16) float s_x[TQ * TN];   // 16 KiB: q-staging / warm-up scores / scratch
  __shared__ float s_t8S[TQ * 9];                // running top-8 (stride 9: bank-safe)
  __shared__ int   s_t8I[TQ * 9];
  __shared__ float s_lsS[TQ * CAP];              // candidate lists
  __shared__ int   s_lsI[TQ * CAP];
  __shared__ float s_thr[TQ];
  __shared__ int   s_cnt[TQ];

  const int h = blockIdx.y, tile = blockIdx.x, tid = threadIdx.x;
  const int wave = tid >> 6, lane = tid & 63;
  const int w0 = wave >> 1, w1 = wave & 1;
  const int lm = lane & 31, lh = lane >> 5;
  const unsigned short* EhiH = EhiP + (size_t)h * NPG * 4096;
  const unsigned short* EloH = EloP + (size_t)h * NPG * 4096;
  const float* y2H = y2g + h * NPAD;

  // ---- prologue: gather query rows via permuted chunks -> s_x, load A ----
  bf16x8 ahi[8], alo[8];
  unsigned short* s_xq = (unsigned short*)s_x;
  {
    int r = tid >> 2, cbase = (tid & 3) * 4;    // 4 chunks of 8 ushort each
    int rx15 = r & 15;
    int q = be[tile * TQ + r];
    int gq = q >> 5, lmq = q & 31;
    const int arow = 32 * w0 + lm;
    const int arx = arow & 15;
    #pragma unroll
    for (int c = 0; c < 4; ++c) {
      int lc = cbase + c;
      *(bf16x8*)&s_xq[r * EMB + (lc ^ rx15) * 8] =
          *(const bf16x8*)&EhiH[pchunk(gq, lc, lmq)];
    }
    __syncthreads();
    #pragma unroll
    for (int ks = 0; ks < 8; ++ks)
      ahi[ks] = *(const bf16x8*)&s_xq[arow * EMB + (((ks * 2 + lh) ^ arx)) * 8];
    __syncthreads();
    #pragma unroll
    for (int c = 0; c < 4; ++c) {
      int lc = cbase + c;
      *(bf16x8*)&s_xq[r * EMB + (lc ^ rx15) * 8] =
          *(const bf16x8*)&EloH[pchunk(gq, lc, lmq)];
    }
    __syncthreads();
    #pragma unroll
    for (int ks = 0; ks < 8; ++ks)
      alo[ks] = *(const bf16x8*)&s_xq[arow * EMB + (((ks * 2 + lh) ^ arx)) * 8];
    __syncthreads();
  }

  // warm-up scan roles: 4 threads per query, each owns a 16-col stripe
  const int qsel = tid >> 2;
  const int csel = tid & 3;
  const int myq = be[tile * TQ + qsel];
  float bs[K]; int bi[K];
  #pragma unroll
  for (int k2 = 0; k2 < K; ++k2) { bs[k2] = 1e30f; bi[k2] = 0x7fffffff; }
  if (tid < TQ) s_cnt[tid] = 0;

  const int bnode = 32 * w1 + lm;                 // node within tile
  // wave's coalesced B pointers: chunk (g=2t+w1, ks, lane)
  const unsigned short* bhp = EhiH + (size_t)w1 * 4096 + lane * 8;
  const unsigned short* blp = EloH + (size_t)w1 * 4096 + lane * 8;

  // ---- warm-up: PH tiles via score dump + private insert ----
  #pragma unroll 1
  for (int t = 0; t < PH; ++t) {
    const size_t goff = (size_t)t * 8192;        // 2 groups * 4096 ushorts
    float ny = y2H[t * TN + bnode];
    floatx16 acc = {0.f, 0.f, 0.f, 0.f, 0.f, 0.f, 0.f, 0.f,
                    0.f, 0.f, 0.f, 0.f, 0.f, 0.f, 0.f, 0.f};
    #pragma unroll
    for (int ks = 0; ks < 8; ++ks) {
      bf16x8 vbh = *(const bf16x8*)(bhp + goff + ks * 512);
      bf16x8 vbl = *(const bf16x8*)(blp + goff + ks * 512);
      acc = __builtin_amdgcn_mfma_f32_32x32x16_bf16(alo[ks], vbh, acc, 0, 0, 0);
      acc = __builtin_amdgcn_mfma_f32_32x32x16_bf16(ahi[ks], vbl, acc, 0, 0, 0);
      acc = __builtin_amdgcn_mfma_f32_32x32x16_bf16(ahi[ks], vbh, acc, 0, 0, 0);
    }
    #pragma unroll
    for (int r = 0; r < 16; ++r) {
      int row = (r & 3) + 8 * (r >> 2) + 4 * lh;
      s_x[(32 * w0 + row) * TN + bnode] = fmaf(-2.f, acc[r], ny);
    }
    __syncthreads();
    int nbp = t * TN;
    #pragma unroll
    for (int s = 0; s < 16; ++s) {
      int j = csel * 16 + ((s + qsel) & 15);
      float sc = s_x[qsel * TN + j];
      int node = nbp + j;
      if (node != myq) insert8(bs, bi, sc, node);
    }
    __syncthreads();
  }

  // ---- first merge: privates -> exact top-8 + thresholds ----
  {
    float* scrS = (float*)s_x;
    int*   scrI = (int*)s_x + TQ * 32;
    #pragma unroll
    for (int k2 = 0; k2 < K; ++k2) {
      scrS[tid * 8 + k2] = bs[k2]; scrI[tid * 8 + k2] = bi[k2];
    }
    __syncthreads();
    if (tid < TQ) {
      int q = tid;
      float ts[K]; int ti[K];
      #pragma unroll
      for (int k2 = 0; k2 < K; ++k2) { ts[k2] = 1e30f; ti[k2] = 0x7fffffff; }
      for (int kk = 0; kk < 32; ++kk) {
        int e = (kk + q) & 31;                     // bank-rotated scan
        insert8(ts, ti, scrS[q * 32 + e], scrI[q * 32 + e]);
      }
      s_thr[q] = ts[K - 1];
      #pragma unroll
      for (int k2 = 0; k2 < K; ++k2) { s_t8S[q * 9 + k2] = ts[k2]; s_t8I[q * 9 + k2] = ti[k2]; }
    }
    __syncthreads();
  }

  float thr16[16];
  #pragma unroll
  for (int r = 0; r < 16; ++r)
    thr16[r] = s_thr[32 * w0 + (r & 3) + 8 * (r >> 2) + 4 * lh];

  // ---- steady state: barrier-free tiles with in-register filtering ----
  #pragma unroll 1
  for (int t = PH; t < NTILES; ++t) {
    if (t == 8 || t == 16 || t == 32 || t == 64) {   // merge point
      __syncthreads();                                // all appends for u<t visible
      if (tid < TQ) {
        int q = tid;
        int myqm = be[tile * TQ + q];
        float ts[K]; int ti[K];
        #pragma unroll
        for (int k2 = 0; k2 < K; ++k2) { ts[k2] = s_t8S[q * 9 + k2]; ti[k2] = s_t8I[q * 9 + k2]; }
        int cnt = s_cnt[q]; if (cnt > CAP) cnt = CAP;
        for (int p = 0; p < cnt; ++p) {
          int iv = s_lsI[q * CAP + p];
          if (iv != myqm) insert8(ts, ti, s_lsS[q * CAP + p], iv);
        }
        s_cnt[q] = 0;
        s_thr[q] = ts[K - 1];
        #pragma unroll
        for (int k2 = 0; k2 < K; ++k2) { s_t8S[q * 9 + k2] = ts[k2]; s_t8I[q * 9 + k2] = ti[k2]; }
      }
      __syncthreads();
      #pragma unroll
      for (int r = 0; r < 16; ++r)
        thr16[r] = s_thr[32 * w0 + (r & 3) + 8 * (r >> 2) + 4 * lh];
    }

    const size_t goff = (size_t)t * 8192;
    float ny = y2H[t * TN + bnode];
    floatx16 acc = {0.f, 0.f, 0.f, 0.f, 0.f, 0.f, 0.f, 0.f,
                    0.f, 0.f, 0.f, 0.f, 0.f, 0.f, 0.f, 0.f};
    #pragma unroll
    for (int ks = 0; ks < 8; ++ks) {
      bf16x8 vbh = *(const bf16x8*)(bhp + goff + ks * 512);
      bf16x8 vbl = *(const bf16x8*)(blp + goff + ks * 512);
      acc = __builtin_amdgcn_mfma_f32_32x32x16_bf16(alo[ks], vbh, acc, 0, 0, 0);
      acc = __builtin_amdgcn_mfma_f32_32x32x16_bf16(ahi[ks], vbl, acc, 0, 0, 0);
      acc = __builtin_amdgcn_mfma_f32_32x32x16_bf16(ahi[ks], vbh, acc, 0, 0, 0);
    }
    const int node = t * TN + bnode;
    #pragma unroll
    for (int r = 0; r < 16; ++r) {
      float sc = fmaf(-2.f, acc[r], ny);
      if (sc < thr16[r]) {                          // rare (self or new top-8)
        int q = 32 * w0 + (r & 3) + 8 * (r >> 2) + 4 * lh;
        int p = atomicAdd(&s_cnt[q], 1);
        if (p < CAP) { s_lsS[q * CAP + p] = sc; s_lsI[q * CAP + p] = node; }
      }
    }
  }

  // ---- final merge + writeout ----
  __syncthreads();
  if (tid < TQ) {
    int q = tid;
    int myqm = be[tile * TQ + q];
    float ts[K]; int ti[K];
    #pragma unroll
    for (int k2 = 0; k2 < K; ++k2) { ts[k2] = s_t8S[q * 9 + k2]; ti[k2] = s_t8I[q * 9 + k2]; }
    int cnt = s_cnt[q]; if (cnt > CAP) cnt = CAP;
    for (int p = 0; p < cnt; ++p) {
      int iv = s_lsI[q * CAP + p];
      if (iv != myqm) insert8(ts, ti, s_lsS[q * CAP + p], iv);
    }
    size_t base = ((size_t)h * NQ + tile * TQ + q) * K;
    #pragma unroll
    for (int k2 = 0; k2 < K; ++k2) samples[base + k2] = ti[k2];
  }
}

// ---------------------------------------------------------------------------
// Kernel B: epilogue (unchanged — verified absmax 0.0).
// ---------------------------------------------------------------------------
__global__ __launch_bounds__(256) void predict_kernel(
    const float* __restrict__ E, const float* __restrict__ F,
    const float* __restrict__ unc, const float* __restrict__ adj,
    const int* __restrict__ be, const int* __restrict__ samples,
    float* __restrict__ out) {
  int b = blockIdx.x;
  int h = threadIdx.x >> 6;
  int lane = threadIdx.x & 63;
  __shared__ float smv[N_HEADS];

  int srcb = be[b];
  int dstb = be[N_BATCH + b];
  const float* Eh = E + (size_t)h * N_NODES * EMB;
  const float* Fh = F + (size_t)h * N_NODES * EMB;
  float2 es = *(const float2*)(Eh + (size_t)srcb * EMB + 2 * lane);
  float2 ed = *(const float2*)(Eh + (size_t)dstb * EMB + 2 * lane);
  float2 fs = *(const float2*)(Fh + (size_t)srcb * EMB + 2 * lane);
  float2 fd = *(const float2*)(Fh + (size_t)dstb * EMB + 2 * lane);
  float u = unc[0];

  float logit[16], dist[16];
  #pragma unroll
  for (int j = 0; j < 16; ++j) {
    bool isrc = (j < 8);
    int qrow = isrc ? b : (N_BATCH + b);
    int s = samples[((size_t)h * NQ + qrow) * K + (j & 7)];
    float2 ev = *(const float2*)(Eh + (size_t)s * EMB + 2 * lane);
    float2 bb = isrc ? es : ed;
    float2 g = isrc ? fd : fs;
    float dx = bb.x - ev.x, dy = bb.y - ev.y;
    float dot = dx * g.x + dy * g.y;
    float nrm = dx * dx + dy * dy;
    #pragma unroll
    for (int o = 32; o > 0; o >>= 1) {
      dot += __shfl_xor(dot, o);
      nrm += __shfl_xor(nrm, o);
    }
    float a = isrc ? adj[(size_t)s * N_NODES + dstb]
                   : adj[(size_t)srcb * N_NODES + s];
    logit[j] = dot + u * (2.0f * a - 1.0f);
    dist[j] = sqrtf(nrm);
  }

  float m = 0.0f;  // sentinel: 1 - 1.0 = 0
  #pragma unroll
  for (int j = 0; j < 16; ++j) m = fmaxf(m, 1.0f - dist[j]);
  float Z = 8.0f * expf(-m);
  float num = 0.0f;
  #pragma unroll
  for (int j = 0; j < 16; ++j) {
    float e = expf(1.0f - dist[j] - m);
    Z += e;
    num += logit[j] * e;
  }
  if (lane == 0) smv[h] = num / Z;
  __syncthreads();
  if (threadIdx.x == 0) {
    float t = 0.25f * (smv[0] + smv[1] + smv[2] + smv[3]);
    out[b] = 1.0f / (1.0f + expf(-t));
  }
}

// ---------------------------------------------------------------------------
extern "C" void kernel_launch(void* const* d_in, const int* in_sizes, int n_in,
                              void* d_out, int out_size, void* d_ws,
                              size_t ws_size, hipStream_t stream) {
  const float* E = (const float*)d_in[0];
  const float* F = (const float*)d_in[1];
  const float* U = (const float*)d_in[2];
  const float* A = (const float*)d_in[3];
  const int* be = (const int*)d_in[4];
  float* out = (float*)d_out;

  // ws layout (256B-aligned): EhiP 10,289,152 | EloP 10,289,152 |
  //   y2g 160,768 | samples 1,048,576   (~21.8 MB)
  char* w = (char*)d_ws;
  unsigned short* EhiP = (unsigned short*)(w);
  unsigned short* EloP = (unsigned short*)(w + 10289152);
  float* y2g = (float*)(w + 20578304);
  int* samples = (int*)(w + 20739072);

  prep_kernel<<<dim3(NPG, N_HEADS), 256, 0, stream>>>(E, EhiP, EloP);
  y2_kernel<<<dim3(NPAD / 4, N_HEADS), 256, 0, stream>>>(E, y2g);
  knn_kernel<<<dim3(NQ / TQ, N_HEADS), 256, 0, stream>>>(EhiP, EloP, y2g, be, samples);
  predict_kernel<<<dim3(N_BATCH), 256, 0, stream>>>(E, F, U, A, be, samples, out);
}

// Round 9
// 889.090 us; speedup vs baseline: 1.2538x; 1.0585x over previous
//
#include <hip/hip_runtime.h>
#include <math.h>
#include <stdint.h>

#define N_HEADS 4
#define N_NODES 10000
#define NPAD 10112           /* multiple of 128 */
#define NPG (NPAD / 32)      /* 316 node-groups of 32 */
#define EMB 128
#define N_BATCH 4096
#define NQ (2 * N_BATCH)     /* 8192 queries: [src(4096), dst(4096)] */
#define K 8
#define TQ 32                /* queries per block */
#define TN 128               /* nodes per iteration (4 groups of 32) */
#define NTILES (NPAD / TN)   /* 79 */
#define PH 2                 /* warm-up tiles (256 nodes) */
#define CAP 41               /* per-query candidate list capacity (odd) */

typedef __attribute__((ext_vector_type(8))) __bf16 bf16x8;
typedef __attribute__((ext_vector_type(8))) unsigned short ushortx8;
typedef __attribute__((ext_vector_type(16))) float floatx16;

// ---------------------------------------------------------------------------
// helpers
// ---------------------------------------------------------------------------
__device__ __forceinline__ unsigned short f2bf(float x) {
  unsigned u = __float_as_uint(x);
  u += 0x7fff + ((u >> 16) & 1);           // round-to-nearest-even
  return (unsigned short)(u >> 16);
}
__device__ __forceinline__ float bf2f(unsigned short h) {
  return __uint_as_float(((unsigned)h) << 16);
}

// sorted ascending top-8 insertion
__device__ __forceinline__ void insert8(float* bs, int* bi, float s, int node) {
  if (s < bs[K - 1]) {
    #pragma unroll
    for (int k2 = K - 1; k2 >= 0; --k2) {
      if (!(s < bs[k2])) break;
      if (k2 < K - 1) { bs[k2 + 1] = bs[k2]; bi[k2 + 1] = bi[k2]; }
      bs[k2] = s; bi[k2] = node;
    }
  }
}

// permuted chunk offset (in ushorts) for row (32g+lm), chunk c (c = ks*2+lh)
// layout: [g][ks][lh][lm] x 8 ushorts  => g*4096 + ks*512 + lh*256 + lm*8
__device__ __forceinline__ size_t pchunk(int g, int c, int lm) {
  return (size_t)g * 4096 + (size_t)(c >> 1) * 512 + (size_t)(c & 1) * 256 + lm * 8;
}

// ---------------------------------------------------------------------------
// Kernel P: split E into bf16 hi/lo in MFMA-B-fragment-permuted layout,
// plus y2 norms. Grid (NPG, N_HEADS), 256 thr. Thread (lm=tid&31, c8=tid>>5)
// handles row 32g+lm, dims [c8*16, c8*16+16). Pad rows -> zeros / y2=1e30.
// ---------------------------------------------------------------------------
__global__ __launch_bounds__(256) void prep_kernel(
    const float* __restrict__ E, unsigned short* __restrict__ EhiP,
    unsigned short* __restrict__ EloP, float* __restrict__ y2g) {
  __shared__ float s_p[8][33];
  const int h = blockIdx.y, g = blockIdx.x;
  const int lm = threadIdx.x & 31, c8 = threadIdx.x >> 5;
  const int n = g * 32 + lm;
  float x[16];
  #pragma unroll
  for (int j = 0; j < 16; ++j) x[j] = 0.f;
  if (n < N_NODES) {
    const float* src = E + (size_t)(h * N_NODES + n) * EMB + c8 * 16;
    #pragma unroll
    for (int j = 0; j < 4; ++j) {
      float4 v = *(const float4*)(src + j * 4);
      x[j * 4 + 0] = v.x; x[j * 4 + 1] = v.y; x[j * 4 + 2] = v.z; x[j * 4 + 3] = v.w;
    }
  }
  float part = 0.f;
  ushortx8 hi[2], lo[2];
  #pragma unroll
  for (int j = 0; j < 16; ++j) {
    part += x[j] * x[j];
    unsigned short hv = f2bf(x[j]);
    unsigned short lv = f2bf(x[j] - bf2f(hv));
    hi[j >> 3][j & 7] = hv;
    lo[j >> 3][j & 7] = lv;
  }
  size_t base = (size_t)h * NPG * 4096;
  #pragma unroll
  for (int lh = 0; lh < 2; ++lh) {
    size_t off = base + pchunk(g, c8 * 2 + lh, lm);
    *(ushortx8*)&EhiP[off] = hi[lh];
    *(ushortx8*)&EloP[off] = lo[lh];
  }
  s_p[c8][lm] = part;
  __syncthreads();
  if (threadIdx.x < 32) {
    int nn = g * 32 + threadIdx.x;
    float s = 0.f;
    #pragma unroll
    for (int j = 0; j < 8; ++j) s += s_p[j][threadIdx.x];
    y2g[h * NPAD + nn] = (nn < N_NODES) ? s : 1e30f;
  }
}

// ---------------------------------------------------------------------------
// Kernel A: barrier-free MFMA knn, 32q x 128n per iteration.
// 1-D grid 1024 with XCD-aware decode: head h -> XCD pair {2h,2h+1} so the
// per-XCD B working set (~5.1 MB hi+lo of one head) is ~L2-resident.
// 4 waves; wave w1 owns node group g = 4t + w1 (32 nodes), all 32 queries.
// A-frags (query hi+lo) in registers; B-frags global->VGPR coalesced from
// the permuted layout (1 KiB lane-linear per load). No per-tile barriers.
// Selection: R7/R8-verified filter-then-refine (warm-up private insert ->
// merged top-8 + thresholds; steady in-register filter + rare LDS append;
// merges at t=4/8/16/32/end). score = y2[n]-2*dot.
// ---------------------------------------------------------------------------
__global__ __launch_bounds__(256, 4) void knn_kernel(
    const unsigned short* __restrict__ EhiP, const unsigned short* __restrict__ EloP,
    const float* __restrict__ y2g, const int* __restrict__ be,
    int* __restrict__ samples) {
  __shared__ __align__(16) float s_x[TQ * TN];   // 16 KiB: q-staging / warm-up scores / scratch
  __shared__ float s_t8S[TQ * 9];                // running top-8 (stride 9)
  __shared__ int   s_t8I[TQ * 9];
  __shared__ float s_lsS[TQ * CAP];              // candidate lists
  __shared__ int   s_lsI[TQ * CAP];
  __shared__ float s_thr[TQ];
  __shared__ int   s_cnt[TQ];

  const int id = blockIdx.x;
  const int h = (id & 7) >> 1;
  const int qt = ((id >> 3) << 1) | (id & 1);    // 0..255
  const int tid = threadIdx.x;
  const int lane = tid & 63;
  const int w1 = tid >> 6;                       // node-group role 0..3
  const int lm = lane & 31, lh = lane >> 5;
  const unsigned short* EhiH = EhiP + (size_t)h * NPG * 4096;
  const unsigned short* EloH = EloP + (size_t)h * NPG * 4096;
  const float* y2H = y2g + h * NPAD;

  // ---- prologue: gather query rows via permuted chunks -> s_x, load A ----
  bf16x8 ahi[8], alo[8];
  unsigned short* s_xq = (unsigned short*)s_x;
  {
    int r = tid >> 3, cbase = (tid & 7) * 2;    // 2 chunks of 8 ushorts each
    int rx15 = r & 15;
    int q = be[qt * TQ + r];
    int gq = q >> 5, lmq = q & 31;
    const int arow = lm;                         // query row 0..31
    const int arx = arow & 15;
    #pragma unroll
    for (int c = 0; c < 2; ++c) {
      int lc = cbase + c;
      *(bf16x8*)&s_xq[r * EMB + (lc ^ rx15) * 8] =
          *(const bf16x8*)&EhiH[pchunk(gq, lc, lmq)];
    }
    __syncthreads();
    #pragma unroll
    for (int ks = 0; ks < 8; ++ks)
      ahi[ks] = *(const bf16x8*)&s_xq[arow * EMB + (((ks * 2 + lh) ^ arx)) * 8];
    __syncthreads();
    #pragma unroll
    for (int c = 0; c < 2; ++c) {
      int lc = cbase + c;
      *(bf16x8*)&s_xq[r * EMB + (lc ^ rx15) * 8] =
          *(const bf16x8*)&EloH[pchunk(gq, lc, lmq)];
    }
    __syncthreads();
    #pragma unroll
    for (int ks = 0; ks < 8; ++ks)
      alo[ks] = *(const bf16x8*)&s_xq[arow * EMB + (((ks * 2 + lh) ^ arx)) * 8];
    __syncthreads();
  }

  // warm-up scan roles: 8 threads per query, each owns a 16-col stripe
  const int qsel = tid >> 3;                     // 0..31
  const int csel = tid & 7;                      // 0..7
  const int myq = be[qt * TQ + qsel];
  float bs[K]; int bi[K];
  #pragma unroll
  for (int k2 = 0; k2 < K; ++k2) { bs[k2] = 1e30f; bi[k2] = 0x7fffffff; }
  if (tid < TQ) s_cnt[tid] = 0;

  const int bnode = 32 * w1 + lm;                // node within 128-tile
  const unsigned short* bhp = EhiH + (size_t)w1 * 4096 + lane * 8;
  const unsigned short* blp = EloH + (size_t)w1 * 4096 + lane * 8;

  // ---- warm-up: PH tiles via score dump + private insert ----
  #pragma unroll 1
  for (int t = 0; t < PH; ++t) {
    const size_t goff = (size_t)t * 16384;       // 4 groups * 4096 ushorts
    float ny = y2H[t * TN + bnode];
    floatx16 acc = {0.f, 0.f, 0.f, 0.f, 0.f, 0.f, 0.f, 0.f,
                    0.f, 0.f, 0.f, 0.f, 0.f, 0.f, 0.f, 0.f};
    #pragma unroll
    for (int ks = 0; ks < 8; ++ks) {
      bf16x8 vbh = *(const bf16x8*)(bhp + goff + ks * 512);
      bf16x8 vbl = *(const bf16x8*)(blp + goff + ks * 512);
      acc = __builtin_amdgcn_mfma_f32_32x32x16_bf16(alo[ks], vbh, acc, 0, 0, 0);
      acc = __builtin_amdgcn_mfma_f32_32x32x16_bf16(ahi[ks], vbl, acc, 0, 0, 0);
      acc = __builtin_amdgcn_mfma_f32_32x32x16_bf16(ahi[ks], vbh, acc, 0, 0, 0);
    }
    #pragma unroll
    for (int r = 0; r < 16; ++r) {
      int row = (r & 3) + 8 * (r >> 2) + 4 * lh;
      s_x[row * TN + bnode] = fmaf(-2.f, acc[r], ny);
    }
    __syncthreads();
    int nbp = t * TN;
    #pragma unroll
    for (int s = 0; s < 16; ++s) {
      int j = csel * 16 + ((s + qsel) & 15);
      float sc = s_x[qsel * TN + j];
      int node = nbp + j;
      if (node != myq) insert8(bs, bi, sc, node);
    }
    __syncthreads();
  }

  // ---- first merge: privates -> exact top-8 + thresholds ----
  {
    float* scrS = (float*)s_x;                   // 2048 floats
    int*   scrI = (int*)s_x + TQ * 64;           // 2048 ints
    #pragma unroll
    for (int k2 = 0; k2 < K; ++k2) {
      scrS[tid * 8 + k2] = bs[k2]; scrI[tid * 8 + k2] = bi[k2];
    }
    __syncthreads();
    if (tid < TQ) {
      int q = tid;
      float ts[K]; int ti[K];
      #pragma unroll
      for (int k2 = 0; k2 < K; ++k2) { ts[k2] = 1e30f; ti[k2] = 0x7fffffff; }
      for (int kk = 0; kk < 64; ++kk) {
        int e = (kk + q) & 63;                   // bank-rotated scan
        insert8(ts, ti, scrS[q * 64 + e], scrI[q * 64 + e]);
      }
      s_thr[q] = ts[K - 1];
      #pragma unroll
      for (int k2 = 0; k2 < K; ++k2) { s_t8S[q * 9 + k2] = ts[k2]; s_t8I[q * 9 + k2] = ti[k2]; }
    }
    __syncthreads();
  }

  float thr16[16];
  #pragma unroll
  for (int r = 0; r < 16; ++r)
    thr16[r] = s_thr[(r & 3) + 8 * (r >> 2) + 4 * lh];

  // ---- steady state: barrier-free tiles with in-register filtering ----
  #pragma unroll 1
  for (int t = PH; t < NTILES; ++t) {
    if (t == 4 || t == 8 || t == 16 || t == 32) {   // merge point
      __syncthreads();
      if (tid < TQ) {
        int q = tid;
        int myqm = be[qt * TQ + q];
        float ts[K]; int ti[K];
        #pragma unroll
        for (int k2 = 0; k2 < K; ++k2) { ts[k2] = s_t8S[q * 9 + k2]; ti[k2] = s_t8I[q * 9 + k2]; }
        int cnt = s_cnt[q]; if (cnt > CAP) cnt = CAP;
        for (int p = 0; p < cnt; ++p) {
          int iv = s_lsI[q * CAP + p];
          if (iv != myqm) insert8(ts, ti, s_lsS[q * CAP + p], iv);
        }
        s_cnt[q] = 0;
        s_thr[q] = ts[K - 1];
        #pragma unroll
        for (int k2 = 0; k2 < K; ++k2) { s_t8S[q * 9 + k2] = ts[k2]; s_t8I[q * 9 + k2] = ti[k2]; }
      }
      __syncthreads();
      #pragma unroll
      for (int r = 0; r < 16; ++r)
        thr16[r] = s_thr[(r & 3) + 8 * (r >> 2) + 4 * lh];
    }

    const size_t goff = (size_t)t * 16384;
    float ny = y2H[t * TN + bnode];
    floatx16 acc = {0.f, 0.f, 0.f, 0.f, 0.f, 0.f, 0.f, 0.f,
                    0.f, 0.f, 0.f, 0.f, 0.f, 0.f, 0.f, 0.f};
    #pragma unroll
    for (int ks = 0; ks < 8; ++ks) {
      bf16x8 vbh = *(const bf16x8*)(bhp + goff + ks * 512);
      bf16x8 vbl = *(const bf16x8*)(blp + goff + ks * 512);
      acc = __builtin_amdgcn_mfma_f32_32x32x16_bf16(alo[ks], vbh, acc, 0, 0, 0);
      acc = __builtin_amdgcn_mfma_f32_32x32x16_bf16(ahi[ks], vbl, acc, 0, 0, 0);
      acc = __builtin_amdgcn_mfma_f32_32x32x16_bf16(ahi[ks], vbh, acc, 0, 0, 0);
    }
    const int node = t * TN + bnode;
    #pragma unroll
    for (int r = 0; r < 16; ++r) {
      float sc = fmaf(-2.f, acc[r], ny);
      if (sc < thr16[r]) {                       // rare (self or new top-8)
        int q = (r & 3) + 8 * (r >> 2) + 4 * lh;
        int p = atomicAdd(&s_cnt[q], 1);
        if (p < CAP) { s_lsS[q * CAP + p] = sc; s_lsI[q * CAP + p] = node; }
      }
    }
  }

  // ---- final merge + writeout ----
  __syncthreads();
  if (tid < TQ) {
    int q = tid;
    int myqm = be[qt * TQ + q];
    float ts[K]; int ti[K];
    #pragma unroll
    for (int k2 = 0; k2 < K; ++k2) { ts[k2] = s_t8S[q * 9 + k2]; ti[k2] = s_t8I[q * 9 + k2]; }
    int cnt = s_cnt[q]; if (cnt > CAP) cnt = CAP;
    for (int p = 0; p < cnt; ++p) {
      int iv = s_lsI[q * CAP + p];
      if (iv != myqm) insert8(ts, ti, s_lsS[q * CAP + p], iv);
    }
    size_t base = ((size_t)h * NQ + qt * TQ + q) * K;
    #pragma unroll
    for (int k2 = 0; k2 < K; ++k2) samples[base + k2] = ti[k2];
  }
}

// ---------------------------------------------------------------------------
// Kernel B: epilogue (unchanged — verified absmax 0.0).
// ---------------------------------------------------------------------------
__global__ __launch_bounds__(256) void predict_kernel(
    const float* __restrict__ E, const float* __restrict__ F,
    const float* __restrict__ unc, const float* __restrict__ adj,
    const int* __restrict__ be, const int* __restrict__ samples,
    float* __restrict__ out) {
  int b = blockIdx.x;
  int h = threadIdx.x >> 6;
  int lane = threadIdx.x & 63;
  __shared__ float smv[N_HEADS];

  int srcb = be[b];
  int dstb = be[N_BATCH + b];
  const float* Eh = E + (size_t)h * N_NODES * EMB;
  const float* Fh = F + (size_t)h * N_NODES * EMB;
  float2 es = *(const float2*)(Eh + (size_t)srcb * EMB + 2 * lane);
  float2 ed = *(const float2*)(Eh + (size_t)dstb * EMB + 2 * lane);
  float2 fs = *(const float2*)(Fh + (size_t)srcb * EMB + 2 * lane);
  float2 fd = *(const float2*)(Fh + (size_t)dstb * EMB + 2 * lane);
  float u = unc[0];

  float logit[16], dist[16];
  #pragma unroll
  for (int j = 0; j < 16; ++j) {
    bool isrc = (j < 8);
    int qrow = isrc ? b : (N_BATCH + b);
    int s = samples[((size_t)h * NQ + qrow) * K + (j & 7)];
    float2 ev = *(const float2*)(Eh + (size_t)s * EMB + 2 * lane);
    float2 bb = isrc ? es : ed;
    float2 g = isrc ? fd : fs;
    float dx = bb.x - ev.x, dy = bb.y - ev.y;
    float dot = dx * g.x + dy * g.y;
    float nrm = dx * dx + dy * dy;
    #pragma unroll
    for (int o = 32; o > 0; o >>= 1) {
      dot += __shfl_xor(dot, o);
      nrm += __shfl_xor(nrm, o);
    }
    float a = isrc ? adj[(size_t)s * N_NODES + dstb]
                   : adj[(size_t)srcb * N_NODES + s];
    logit[j] = dot + u * (2.0f * a - 1.0f);
    dist[j] = sqrtf(nrm);
  }

  float m = 0.0f;  // sentinel: 1 - 1.0 = 0
  #pragma unroll
  for (int j = 0; j < 16; ++j) m = fmaxf(m, 1.0f - dist[j]);
  float Z = 8.0f * expf(-m);
  float num = 0.0f;
  #pragma unroll
  for (int j = 0; j < 16; ++j) {
    float e = expf(1.0f - dist[j] - m);
    Z += e;
    num += logit[j] * e;
  }
  if (lane == 0) smv[h] = num / Z;
  __syncthreads();
  if (threadIdx.x == 0) {
    float t = 0.25f * (smv[0] + smv[1] + smv[2] + smv[3]);
    out[b] = 1.0f / (1.0f + expf(-t));
  }
}

// ---------------------------------------------------------------------------
extern "C" void kernel_launch(void* const* d_in, const int* in_sizes, int n_in,
                              void* d_out, int out_size, void* d_ws,
                              size_t ws_size, hipStream_t stream) {
  const float* E = (const float*)d_in[0];
  const float* F = (const float*)d_in[1];
  const float* U = (const float*)d_in[2];
  const float* A = (const float*)d_in[3];
  const int* be = (const int*)d_in[4];
  float* out = (float*)d_out;

  // ws layout (256B-aligned): EhiP 10,354,688 | EloP 10,354,688 |
  //   y2g 162,048 | samples 1,048,576   (~21.9 MB)
  char* w = (char*)d_ws;
  unsigned short* EhiP = (unsigned short*)(w);
  unsigned short* EloP = (unsigned short*)(w + 10354688);
  float* y2g = (float*)(w + 20709376);
  int* samples = (int*)(w + 20871424);

  prep_kernel<<<dim3(NPG, N_HEADS), 256, 0, stream>>>(E, EhiP, EloP, y2g);
  knn_kernel<<<dim3((NQ / TQ) * N_HEADS), 256, 0, stream>>>(EhiP, EloP, y2g, be, samples);
  predict_kernel<<<dim3(N_BATCH), 256, 0, stream>>>(E, F, U, A, be, samples, out);
}

// Round 10
// 803.708 us; speedup vs baseline: 1.3869x; 1.1062x over previous
//
#include <hip/hip_runtime.h>
#include <math.h>
#include <stdint.h>

#define N_HEADS 4
#define N_NODES 10000
#define NPAD 10112           /* multiple of 128 */
#define NPG (NPAD / 32)      /* 316 node-groups of 32 */
#define EMB 128
#define N_BATCH 4096
#define NQ (2 * N_BATCH)     /* 8192 queries: [src(4096), dst(4096)] */
#define K 8
#define TQ 32                /* queries per block */
#define TN 128               /* nodes per iteration (4 groups of 32) */
#define NTILES (NPAD / TN)   /* 79 */
#define PH 2                 /* warm-up tiles (256 nodes) */
#define CAP 41               /* per-query candidate list capacity (odd) */

typedef __attribute__((ext_vector_type(8))) __bf16 bf16x8;
typedef __attribute__((ext_vector_type(8))) unsigned short ushortx8;
typedef __attribute__((ext_vector_type(16))) float floatx16;

// ---------------------------------------------------------------------------
// helpers
// ---------------------------------------------------------------------------
__device__ __forceinline__ unsigned short f2bf(float x) {
  unsigned u = __float_as_uint(x);
  u += 0x7fff + ((u >> 16) & 1);           // round-to-nearest-even
  return (unsigned short)(u >> 16);
}
__device__ __forceinline__ float bf2f(unsigned short h) {
  return __uint_as_float(((unsigned)h) << 16);
}
// bf16 bits rounded toward +inf (conservative threshold)
__device__ __forceinline__ uint32_t bfup(float f) {
  uint32_t u = __float_as_uint(f);
  return (f >= 0.f) ? ((u + 0xFFFFu) >> 16) : (u >> 16);
}

// sorted ascending top-8 insertion
__device__ __forceinline__ void insert8(float* bs, int* bi, float s, int node) {
  if (s < bs[K - 1]) {
    #pragma unroll
    for (int k2 = K - 1; k2 >= 0; --k2) {
      if (!(s < bs[k2])) break;
      if (k2 < K - 1) { bs[k2 + 1] = bs[k2]; bi[k2 + 1] = bi[k2]; }
      bs[k2] = s; bi[k2] = node;
    }
  }
}

// permuted chunk offset (in ushorts) for row (32g+lm), chunk c (c = ks*2+lh)
// layout: [g][ks][lh][lm] x 8 ushorts  => g*4096 + ks*512 + lh*256 + lm*8
__device__ __forceinline__ size_t pchunk(int g, int c, int lm) {
  return (size_t)g * 4096 + (size_t)(c >> 1) * 512 + (size_t)(c & 1) * 256 + lm * 8;
}

// ---------------------------------------------------------------------------
// Kernel P: split E into bf16 hi/lo in MFMA-B-fragment-permuted layout,
// plus y2 norms. Grid (NPG, N_HEADS), 256 thr. Thread (lm=tid&31, c8=tid>>5)
// handles row 32g+lm, dims [c8*16, c8*16+16). Pad rows -> zeros / y2=1e30.
// ---------------------------------------------------------------------------
__global__ __launch_bounds__(256) void prep_kernel(
    const float* __restrict__ E, unsigned short* __restrict__ EhiP,
    unsigned short* __restrict__ EloP, float* __restrict__ y2g) {
  __shared__ float s_p[8][33];
  const int h = blockIdx.y, g = blockIdx.x;
  const int lm = threadIdx.x & 31, c8 = threadIdx.x >> 5;
  const int n = g * 32 + lm;
  float x[16];
  #pragma unroll
  for (int j = 0; j < 16; ++j) x[j] = 0.f;
  if (n < N_NODES) {
    const float* src = E + (size_t)(h * N_NODES + n) * EMB + c8 * 16;
    #pragma unroll
    for (int j = 0; j < 4; ++j) {
      float4 v = *(const float4*)(src + j * 4);
      x[j * 4 + 0] = v.x; x[j * 4 + 1] = v.y; x[j * 4 + 2] = v.z; x[j * 4 + 3] = v.w;
    }
  }
  float part = 0.f;
  ushortx8 hi[2], lo[2];
  #pragma unroll
  for (int j = 0; j < 16; ++j) {
    part += x[j] * x[j];
    unsigned short hv = f2bf(x[j]);
    unsigned short lv = f2bf(x[j] - bf2f(hv));
    hi[j >> 3][j & 7] = hv;
    lo[j >> 3][j & 7] = lv;
  }
  size_t base = (size_t)h * NPG * 4096;
  #pragma unroll
  for (int lh = 0; lh < 2; ++lh) {
    size_t off = base + pchunk(g, c8 * 2 + lh, lm);
    *(ushortx8*)&EhiP[off] = hi[lh];
    *(ushortx8*)&EloP[off] = lo[lh];
  }
  s_p[c8][lm] = part;
  __syncthreads();
  if (threadIdx.x < 32) {
    int nn = g * 32 + threadIdx.x;
    float s = 0.f;
    #pragma unroll
    for (int j = 0; j < 8; ++j) s += s_p[j][threadIdx.x];
    y2g[h * NPAD + nn] = (nn < N_NODES) ? s : 1e30f;
  }
}

// ---------------------------------------------------------------------------
// Kernel A: barrier-free MFMA knn, 32q x 128n per iteration, low-VGPR.
// vs R9: query-lo A-frags live in LDS (s_alo, written once, swizzled,
// read 8x16B per tile — no barriers), thresholds cached as 8 packed
// round-up bf16 pairs. Demand ~105 regs < 128 => no spill at (256,4).
// 1-D grid 1024, XCD-aware decode (head -> XCD pair). Wave w1 owns node
// group 4t+w1; B-frags global->VGPR coalesced from permuted layout.
// Selection: verified filter-then-refine (R7-R9). score = y2[n]-2*dot.
// ---------------------------------------------------------------------------
__global__ __launch_bounds__(256, 4) void knn_kernel(
    const unsigned short* __restrict__ EhiP, const unsigned short* __restrict__ EloP,
    const float* __restrict__ y2g, const int* __restrict__ be,
    int* __restrict__ samples) {
  __shared__ __align__(16) float s_x[TQ * TN];              // 16 KiB
  __shared__ __align__(16) unsigned short s_alo[TQ * EMB];  // 8 KiB, persistent
  __shared__ float s_t8S[TQ * 9];
  __shared__ int   s_t8I[TQ * 9];
  __shared__ float s_lsS[TQ * CAP];
  __shared__ int   s_lsI[TQ * CAP];
  __shared__ float s_thr[TQ];
  __shared__ int   s_cnt[TQ];

  const int id = blockIdx.x;
  const int h = (id & 7) >> 1;
  const int qt = ((id >> 3) << 1) | (id & 1);    // 0..255
  const int tid = threadIdx.x;
  const int lane = tid & 63;
  const int w1 = tid >> 6;                       // node-group role 0..3
  const int lm = lane & 31, lh = lane >> 5;
  const unsigned short* EhiH = EhiP + (size_t)h * NPG * 4096;
  const unsigned short* EloH = EloP + (size_t)h * NPG * 4096;
  const float* y2H = y2g + h * NPAD;

  // ---- prologue: gather query rows -> s_x (hi, to regs) / s_alo (lo) ----
  bf16x8 ahi[8];
  unsigned short* s_xq = (unsigned short*)s_x;
  {
    int r = tid >> 3, cb = (tid & 7) * 2;        // 2 chunks of 8 ushorts each
    int rx15 = r & 15;
    int q = be[qt * TQ + r];
    int gq = q >> 5, lmq = q & 31;
    const int arx = lm & 15;
    #pragma unroll
    for (int c = 0; c < 2; ++c) {
      int lc = cb + c;
      *(bf16x8*)&s_xq[r * EMB + (lc ^ rx15) * 8] =
          *(const bf16x8*)&EhiH[pchunk(gq, lc, lmq)];
    }
    __syncthreads();
    #pragma unroll
    for (int ks = 0; ks < 8; ++ks)
      ahi[ks] = *(const bf16x8*)&s_xq[lm * EMB + (((ks * 2 + lh) ^ arx)) * 8];
    __syncthreads();
    #pragma unroll
    for (int c = 0; c < 2; ++c) {
      int lc = cb + c;
      *(bf16x8*)&s_alo[r * EMB + (lc ^ rx15) * 8] =
          *(const bf16x8*)&EloH[pchunk(gq, lc, lmq)];
    }
    __syncthreads();
  }

  // warm-up scan roles: 8 threads per query, each owns a 16-col stripe
  const int qsel = tid >> 3;                     // 0..31
  const int csel = tid & 7;                      // 0..7
  const int myq = be[qt * TQ + qsel];
  float bs[K]; int bi[K];
  #pragma unroll
  for (int k2 = 0; k2 < K; ++k2) { bs[k2] = 1e30f; bi[k2] = 0x7fffffff; }
  if (tid < TQ) s_cnt[tid] = 0;

  const int bnode = 32 * w1 + lm;                // node within 128-tile
  const int arx = lm & 15;
  const unsigned short* bhp = EhiH + (size_t)w1 * 4096 + lane * 8;
  const unsigned short* blp = EloH + (size_t)w1 * 4096 + lane * 8;

  // ---- warm-up: PH tiles via score dump + private insert ----
  #pragma unroll 1
  for (int t = 0; t < PH; ++t) {
    const size_t goff = (size_t)t * 16384;       // 4 groups * 4096 ushorts
    float ny = y2H[t * TN + bnode];
    floatx16 acc = {0.f, 0.f, 0.f, 0.f, 0.f, 0.f, 0.f, 0.f,
                    0.f, 0.f, 0.f, 0.f, 0.f, 0.f, 0.f, 0.f};
    #pragma unroll
    for (int ks = 0; ks < 8; ++ks) {
      bf16x8 va = *(const bf16x8*)&s_alo[lm * EMB + (((ks * 2 + lh) ^ arx)) * 8];
      bf16x8 vbh = *(const bf16x8*)(bhp + goff + ks * 512);
      bf16x8 vbl = *(const bf16x8*)(blp + goff + ks * 512);
      acc = __builtin_amdgcn_mfma_f32_32x32x16_bf16(va, vbh, acc, 0, 0, 0);
      acc = __builtin_amdgcn_mfma_f32_32x32x16_bf16(ahi[ks], vbl, acc, 0, 0, 0);
      acc = __builtin_amdgcn_mfma_f32_32x32x16_bf16(ahi[ks], vbh, acc, 0, 0, 0);
    }
    #pragma unroll
    for (int r = 0; r < 16; ++r) {
      int row = (r & 3) + 8 * (r >> 2) + 4 * lh;
      s_x[row * TN + bnode] = fmaf(-2.f, acc[r], ny);
    }
    __syncthreads();
    int nbp = t * TN;
    #pragma unroll
    for (int s = 0; s < 16; ++s) {
      int j = csel * 16 + ((s + qsel) & 15);
      float sc = s_x[qsel * TN + j];
      int node = nbp + j;
      if (node != myq) insert8(bs, bi, sc, node);
    }
    __syncthreads();
  }

  // ---- first merge: privates -> exact top-8 + thresholds ----
  {
    float* scrS = (float*)s_x;                   // 2048 floats
    int*   scrI = (int*)s_x + TQ * 64;           // 2048 ints
    #pragma unroll
    for (int k2 = 0; k2 < K; ++k2) {
      scrS[tid * 8 + k2] = bs[k2]; scrI[tid * 8 + k2] = bi[k2];
    }
    __syncthreads();
    if (tid < TQ) {
      int q = tid;
      float ts[K]; int ti[K];
      #pragma unroll
      for (int k2 = 0; k2 < K; ++k2) { ts[k2] = 1e30f; ti[k2] = 0x7fffffff; }
      for (int kk = 0; kk < 64; ++kk) {
        int e = (kk + q) & 63;                   // bank-rotated scan
        insert8(ts, ti, scrS[q * 64 + e], scrI[q * 64 + e]);
      }
      s_thr[q] = ts[K - 1];
      #pragma unroll
      for (int k2 = 0; k2 < K; ++k2) { s_t8S[q * 9 + k2] = ts[k2]; s_t8I[q * 9 + k2] = ti[k2]; }
    }
    __syncthreads();
  }

  // packed round-up bf16 thresholds: 8 regs for 16 rows
  uint32_t thrp[8];
  #pragma unroll
  for (int j = 0; j < 8; ++j) {
    int r0 = 2 * j, r1 = 2 * j + 1;
    float t0 = s_thr[(r0 & 3) + 8 * (r0 >> 2) + 4 * lh];
    float t1 = s_thr[(r1 & 3) + 8 * (r1 >> 2) + 4 * lh];
    thrp[j] = bfup(t0) | (bfup(t1) << 16);
  }

  // ---- steady state: barrier-free tiles with in-register filtering ----
  #pragma unroll 1
  for (int t = PH; t < NTILES; ++t) {
    if (t == 4 || t == 8 || t == 16 || t == 32) {   // merge point
      __syncthreads();
      if (tid < TQ) {
        int q = tid;
        int myqm = be[qt * TQ + q];
        float ts[K]; int ti[K];
        #pragma unroll
        for (int k2 = 0; k2 < K; ++k2) { ts[k2] = s_t8S[q * 9 + k2]; ti[k2] = s_t8I[q * 9 + k2]; }
        int cnt = s_cnt[q]; if (cnt > CAP) cnt = CAP;
        for (int p = 0; p < cnt; ++p) {
          int iv = s_lsI[q * CAP + p];
          if (iv != myqm) insert8(ts, ti, s_lsS[q * CAP + p], iv);
        }
        s_cnt[q] = 0;
        s_thr[q] = ts[K - 1];
        #pragma unroll
        for (int k2 = 0; k2 < K; ++k2) { s_t8S[q * 9 + k2] = ts[k2]; s_t8I[q * 9 + k2] = ti[k2]; }
      }
      __syncthreads();
      #pragma unroll
      for (int j = 0; j < 8; ++j) {
        int r0 = 2 * j, r1 = 2 * j + 1;
        float t0 = s_thr[(r0 & 3) + 8 * (r0 >> 2) + 4 * lh];
        float t1 = s_thr[(r1 & 3) + 8 * (r1 >> 2) + 4 * lh];
        thrp[j] = bfup(t0) | (bfup(t1) << 16);
      }
    }

    const size_t goff = (size_t)t * 16384;
    float ny = y2H[t * TN + bnode];
    floatx16 acc = {0.f, 0.f, 0.f, 0.f, 0.f, 0.f, 0.f, 0.f,
                    0.f, 0.f, 0.f, 0.f, 0.f, 0.f, 0.f, 0.f};
    #pragma unroll
    for (int ks = 0; ks < 8; ++ks) {
      bf16x8 va = *(const bf16x8*)&s_alo[lm * EMB + (((ks * 2 + lh) ^ arx)) * 8];
      bf16x8 vbh = *(const bf16x8*)(bhp + goff + ks * 512);
      bf16x8 vbl = *(const bf16x8*)(blp + goff + ks * 512);
      acc = __builtin_amdgcn_mfma_f32_32x32x16_bf16(va, vbh, acc, 0, 0, 0);
      acc = __builtin_amdgcn_mfma_f32_32x32x16_bf16(ahi[ks], vbl, acc, 0, 0, 0);
      acc = __builtin_amdgcn_mfma_f32_32x32x16_bf16(ahi[ks], vbh, acc, 0, 0, 0);
    }
    const int node = t * TN + bnode;
    #pragma unroll
    for (int r = 0; r < 16; ++r) {
      float sc = fmaf(-2.f, acc[r], ny);
      float th = (r & 1) ? __uint_as_float(thrp[r >> 1] & 0xFFFF0000u)
                         : __uint_as_float(thrp[r >> 1] << 16);
      if (sc < th) {                             // rare (self or new top-8)
        int q = (r & 3) + 8 * (r >> 2) + 4 * lh;
        int p = atomicAdd(&s_cnt[q], 1);
        if (p < CAP) { s_lsS[q * CAP + p] = sc; s_lsI[q * CAP + p] = node; }
      }
    }
  }

  // ---- final merge + writeout ----
  __syncthreads();
  if (tid < TQ) {
    int q = tid;
    int myqm = be[qt * TQ + q];
    float ts[K]; int ti[K];
    #pragma unroll
    for (int k2 = 0; k2 < K; ++k2) { ts[k2] = s_t8S[q * 9 + k2]; ti[k2] = s_t8I[q * 9 + k2]; }
    int cnt = s_cnt[q]; if (cnt > CAP) cnt = CAP;
    for (int p = 0; p < cnt; ++p) {
      int iv = s_lsI[q * CAP + p];
      if (iv != myqm) insert8(ts, ti, s_lsS[q * CAP + p], iv);
    }
    size_t base = ((size_t)h * NQ + qt * TQ + q) * K;
    #pragma unroll
    for (int k2 = 0; k2 < K; ++k2) samples[base + k2] = ti[k2];
  }
}

// ---------------------------------------------------------------------------
// Kernel B: epilogue (unchanged — verified absmax 0.0).
// ---------------------------------------------------------------------------
__global__ __launch_bounds__(256) void predict_kernel(
    const float* __restrict__ E, const float* __restrict__ F,
    const float* __restrict__ unc, const float* __restrict__ adj,
    const int* __restrict__ be, const int* __restrict__ samples,
    float* __restrict__ out) {
  int b = blockIdx.x;
  int h = threadIdx.x >> 6;
  int lane = threadIdx.x & 63;
  __shared__ float smv[N_HEADS];

  int srcb = be[b];
  int dstb = be[N_BATCH + b];
  const float* Eh = E + (size_t)h * N_NODES * EMB;
  const float* Fh = F + (size_t)h * N_NODES * EMB;
  float2 es = *(const float2*)(Eh + (size_t)srcb * EMB + 2 * lane);
  float2 ed = *(const float2*)(Eh + (size_t)dstb * EMB + 2 * lane);
  float2 fs = *(const float2*)(Fh + (size_t)srcb * EMB + 2 * lane);
  float2 fd = *(const float2*)(Fh + (size_t)dstb * EMB + 2 * lane);
  float u = unc[0];

  float logit[16], dist[16];
  #pragma unroll
  for (int j = 0; j < 16; ++j) {
    bool isrc = (j < 8);
    int qrow = isrc ? b : (N_BATCH + b);
    int s = samples[((size_t)h * NQ + qrow) * K + (j & 7)];
    float2 ev = *(const float2*)(Eh + (size_t)s * EMB + 2 * lane);
    float2 bb = isrc ? es : ed;
    float2 g = isrc ? fd : fs;
    float dx = bb.x - ev.x, dy = bb.y - ev.y;
    float dot = dx * g.x + dy * g.y;
    float nrm = dx * dx + dy * dy;
    #pragma unroll
    for (int o = 32; o > 0; o >>= 1) {
      dot += __shfl_xor(dot, o);
      nrm += __shfl_xor(nrm, o);
    }
    float a = isrc ? adj[(size_t)s * N_NODES + dstb]
                   : adj[(size_t)srcb * N_NODES + s];
    logit[j] = dot + u * (2.0f * a - 1.0f);
    dist[j] = sqrtf(nrm);
  }

  float m = 0.0f;  // sentinel: 1 - 1.0 = 0
  #pragma unroll
  for (int j = 0; j < 16; ++j) m = fmaxf(m, 1.0f - dist[j]);
  float Z = 8.0f * expf(-m);
  float num = 0.0f;
  #pragma unroll
  for (int j = 0; j < 16; ++j) {
    float e = expf(1.0f - dist[j] - m);
    Z += e;
    num += logit[j] * e;
  }
  if (lane == 0) smv[h] = num / Z;
  __syncthreads();
  if (threadIdx.x == 0) {
    float t = 0.25f * (smv[0] + smv[1] + smv[2] + smv[3]);
    out[b] = 1.0f / (1.0f + expf(-t));
  }
}

// ---------------------------------------------------------------------------
extern "C" void kernel_launch(void* const* d_in, const int* in_sizes, int n_in,
                              void* d_out, int out_size, void* d_ws,
                              size_t ws_size, hipStream_t stream) {
  const float* E = (const float*)d_in[0];
  const float* F = (const float*)d_in[1];
  const float* U = (const float*)d_in[2];
  const float* A = (const float*)d_in[3];
  const int* be = (const int*)d_in[4];
  float* out = (float*)d_out;

  // ws layout (256B-aligned): EhiP 10,354,688 | EloP 10,354,688 |
  //   y2g 162,048 | samples 1,048,576   (~21.9 MB)
  char* w = (char*)d_ws;
  unsigned short* EhiP = (unsigned short*)(w);
  unsigned short* EloP = (unsigned short*)(w + 10354688);
  float* y2g = (float*)(w + 20709376);
  int* samples = (int*)(w + 20871424);

  prep_kernel<<<dim3(NPG, N_HEADS), 256, 0, stream>>>(E, EhiP, EloP, y2g);
  knn_kernel<<<dim3((NQ / TQ) * N_HEADS), 256, 0, stream>>>(EhiP, EloP, y2g, be, samples);
  predict_kernel<<<dim3(N_BATCH), 256, 0, stream>>>(E, F, U, A, be, samples, out);
}